// Round 2
// baseline (276.996 us; speedup 1.0000x reference)
//
#include <hip/hip_runtime.h>

// HairBundleSDE: dx = f(t, x) elementwise, N=8388608 rows x 5 f32 state vars.
// Traffic 335.5MB logical => ~53us floor at 6.29 TB/s achievable copy BW (m13).
//
// R7: persistent grid-stride blocks + register prefetch double-buffer,
// on top of R6's wave-synchronous LDS transpose structure.
//  - 2048 blocks x 4 chunks (was 8192 x 1): the per-block prologue
//    (kernarg s_load ~600cy, tp[0] HBM load ~900cy, sinf, address setup)
//    is paid 4x less often; it was ~2000cy of zero-traffic block residency
//    against ~4000cy of BW-work per block.
//  - Chunk i+1's five global_load_dwordx4 are issued right after chunk i's
//    LDS gather-read, so HBM latency overlaps compute + scatter + store.
//  - Wave-synchronous, zero __syncthreads (R6): each wave owns a private
//    5KB LDS window; gather/scatter are lane-private (thread t owns floats
//    [20t,20t+20) of the window), scatter is IN PLACE. Single 20KB buffer
//    -> 8 blocks/CU LDS-wise. DS-op program order + compiler lgkmcnt
//    handle the WAR between iterations (wave_barrier pins ordering).
//  - LDS row stride = 20 floats: each 8-lane group's b128 gather tiles all
//    32 banks exactly once -> conflict-free (SQ_LDS_BANK_CONFLICT = 0).
//  - Nontemporal load/store: both streams touched exactly once.

namespace {

typedef float f32x4 __attribute__((ext_vector_type(4)));

constexpr float K_GS      = 0.75f;
constexpr float K_SP      = 0.6f;
constexpr float D0        = 0.5f;
constexpr float DELTA_INV = 5.0f;   // 1/0.2
constexpr float F_MAX     = 1.0f;
constexpr float S_CA      = 0.7f;
constexpr float LAMA_INV  = 0.1f;   // 1/LAM_A
constexpr float AMP       = 0.3f;
constexpr float OMEGA     = 6.283185307179586f;

constexpr int BLOCK       = 256;
constexpr int ROWS_PER_T  = 4;
constexpr int CHUNK_ROWS  = BLOCK * ROWS_PER_T;          // 1024 rows/chunk
constexpr int CHUNK_F4    = CHUNK_ROWS * 5 / 4;          // 1280 f32x4 = 20KB
constexpr int WAVE_F4     = 64 * ROWS_PER_T * 5 / 4;     // 320 f32x4 = 5KB/wave
constexpr int CPB         = 4;                           // chunks per block

__device__ __forceinline__ void compute_row(float X, float Xa, float pm, float pgs, float pt,
                                            float force, float* o) {
    float d   = X - Xa;
    float z   = (d - D0) * DELTA_INV;
    float p   = 1.0f / (1.0f + __expf(-z));          // sigmoid((X-Xa-D0)/DELTA)
    float fgs = K_GS * (d - D0 * p);
    o[0] = force - fgs - K_SP * X;                   // dX   (LAM = 1)
    o[1] = (fgs - (F_MAX - S_CA * pm)) * LAMA_INV;   // dXa
    o[2] = 1.5f * p * (1.0f - pm) - pm;              // dpm  (TAU_M = 1)
    o[3] = (1.2f * p * (1.0f - pgs) - pgs) * 0.2f;   // dpgs (TAU_GS = 5)
    o[4] = (0.8f * p * (1.0f - pt)  - pt)  * 0.1f;   // dpt  (TAU_T = 10)
}

} // namespace

__global__ __launch_bounds__(BLOCK) void hb_kernel(
        const float* __restrict__ tp,
        const float* __restrict__ xp,
        float* __restrict__ op,
        long long nrows) {
    __shared__ f32x4 s[CHUNK_F4];   // 20 KB, four wave-private 5KB windows

    const int tid   = threadIdx.x;
    const int lane  = tid & 63;
    const int wbase = (tid >> 6) * WAVE_F4;

    f32x4* sw = s + wbase;
    f32x4* r4 = reinterpret_cast<f32x4*>(reinterpret_cast<float*>(sw) + lane * 20);

    // force = AMP * sin(OMEGA * t); once per persistent block, fully hidden.
    const float force = AMP * sinf(OMEGA * tp[0]);

    const long long nchunks = (nrows + CHUNK_ROWS - 1) / CHUNK_ROWS;
    const long long nfull   = nrows / CHUNK_ROWS;          // full chunks
    const long long cstart  = (long long)blockIdx.x * CPB;
    long long cend = cstart + CPB; if (cend > nchunks) cend = nchunks;
    long long cfe  = cend < nfull ? cend : nfull;          // full-chunk end

    long long c = cstart;
    if (c < cfe) {
        // ---- prefetch chunk c into registers ----
        f32x4 rin[5];
        {
            const f32x4* g = reinterpret_cast<const f32x4*>(xp + c * (long long)CHUNK_ROWS * 5)
                             + wbase + lane;
#pragma unroll
            for (int k = 0; k < 5; ++k) rin[k] = __builtin_nontemporal_load(g + 64 * k);
        }

        for (; c < cfe; ++c) {
            // ---- stage 1: registers -> LDS (wave-private coalesced window) ----
#pragma unroll
            for (int k = 0; k < 5; ++k) sw[64 * k + lane] = rin[k];
            __builtin_amdgcn_wave_barrier();

            // ---- stage 2a: lane-private row gather (conflict-free) ----
            float vals[20];
#pragma unroll
            for (int k = 0; k < 5; ++k) {
                f32x4 v = r4[k];
                vals[4*k+0] = v.x; vals[4*k+1] = v.y; vals[4*k+2] = v.z; vals[4*k+3] = v.w;
            }

            // ---- prefetch chunk c+1: HBM latency hides under compute+store ----
            if (c + 1 < cfe) {
                const f32x4* g = reinterpret_cast<const f32x4*>(
                                     xp + (c + 1) * (long long)CHUNK_ROWS * 5) + wbase + lane;
#pragma unroll
                for (int k = 0; k < 5; ++k) rin[k] = __builtin_nontemporal_load(g + 64 * k);
            }

            // ---- stage 2b: compute 4 rows, scatter results IN PLACE ----
#pragma unroll
            for (int r = 0; r < ROWS_PER_T; ++r)   // args by value -> in-place safe
                compute_row(vals[5*r+0], vals[5*r+1], vals[5*r+2], vals[5*r+3], vals[5*r+4],
                            force, &vals[5*r]);

#pragma unroll
            for (int k = 0; k < 5; ++k)
                r4[k] = (f32x4){vals[4*k+0], vals[4*k+1], vals[4*k+2], vals[4*k+3]};
            __builtin_amdgcn_wave_barrier();

            // ---- stage 3: LDS -> global (wave-coalesced) ----
            f32x4* gd = reinterpret_cast<f32x4*>(op + c * (long long)CHUNK_ROWS * 5)
                        + wbase + lane;
#pragma unroll
            for (int k = 0; k < 5; ++k)
                __builtin_nontemporal_store(sw[64 * k + lane], gd + 64 * k);
            __builtin_amdgcn_wave_barrier();   // pin next iter's ds_write after these reads
        }
    }

    // ---- tail: partial last chunk (not taken for N=8388608) ----
    if (nfull < cend && nfull >= cstart) {
        for (long long r = nfull * (long long)CHUNK_ROWS + tid; r < nrows; r += BLOCK) {
            float in[5], out[5];
            for (int j = 0; j < 5; ++j) in[j] = xp[r*5 + j];
            compute_row(in[0], in[1], in[2], in[3], in[4], force, out);
            for (int j = 0; j < 5; ++j) op[r*5 + j] = out[j];
        }
    }
}

extern "C" void kernel_launch(void* const* d_in, const int* in_sizes, int n_in,
                              void* d_out, int out_size, void* d_ws, size_t ws_size,
                              hipStream_t stream) {
    const float* t = (const float*)d_in[0];
    const float* x = (const float*)d_in[1];
    float* out     = (float*)d_out;

    const long long nrows   = (long long)in_sizes[1] / 5;                 // 8388608
    const long long nchunks = (nrows + CHUNK_ROWS - 1) / CHUNK_ROWS;      // 8192
    const int grid = (int)((nchunks + CPB - 1) / CPB);                    // 2048

    hb_kernel<<<grid, BLOCK, 0, stream>>>(t, x, out, nrows);
}